// Round 4
// baseline (768.698 us; speedup 1.0000x reference)
//
#include <hip/hip_runtime.h>
#include <hip/hip_bf16.h>
#include <math.h>

// Problem constants
#define BB 4
#define MM 20
#define LL 200
#define INC 2048
#define C1 512
#define C2 256
#define CDIM 300
#define DC1 512
#define DC2 256
#define SDIM 1024
#define BM 80           // B*M
#define L2 100          // L/2
#define L4 50           // L/4

typedef unsigned short u16;
typedef __attribute__((ext_vector_type(8))) short bf16x8;
typedef __attribute__((ext_vector_type(4))) float f32x4;

__device__ __forceinline__ u16 f2bf_rne(float f) {
  unsigned u = __float_as_uint(f);
  unsigned r = u + 0x7FFFu + ((u >> 16) & 1u);
  return (u16)(r >> 16);
}
__device__ __forceinline__ float bf2f(u16 v) {
  return __uint_as_float(((unsigned)v) << 16);
}

// async global -> LDS, 16 B per lane. LDS dest = wave-uniform base + lane*16.
// Global SOURCE is per-lane (arbitrary); dest is linear.
__device__ __forceinline__ void gload16(const u16* g, u16* l) {
  __builtin_amdgcn_global_load_lds(
      (const __attribute__((address_space(1))) void*)g,
      (__attribute__((address_space(3))) void*)l, 16, 0, 0);
}

// ---------------- batch fp32 -> bf16, 2-row zero pad, GLOBAL XOR-SWIZZLE ----------------
// Layout [80][204][2048] bf16; within each (prow, 64-ci block) the 16B unit u is
// stored at u ^ (prow&7). Consumed by the conv GEMMs' row-major A tiles
// (linear gload_lds dest + pre-swizzled source + XOR on read).
__global__ void k_cast_pad_batch(const float* __restrict__ in, u16* __restrict__ out) {
  int idx = blockIdx.x * 256 + threadIdx.x;   // octet index
  if (idx >= 80 * 204 * 256) return;
  int c8 = idx % 256;                         // 16B unit within row (0..255)
  int pi = (idx / 256) % 204;
  int n  = idx / (256 * 204);
  uint4 o = make_uint4(0u, 0u, 0u, 0u);
  if (pi >= 2 && pi < 202) {
    const float* p = in + ((long long)(n * 200 + pi - 2) * 2048 + c8 * 8);
    float4 a = *(const float4*)p;
    float4 b = *(const float4*)(p + 4);
    o.x = (unsigned)f2bf_rne(a.x) | ((unsigned)f2bf_rne(a.y) << 16);
    o.y = (unsigned)f2bf_rne(a.z) | ((unsigned)f2bf_rne(a.w) << 16);
    o.z = (unsigned)f2bf_rne(b.x) | ((unsigned)f2bf_rne(b.y) << 16);
    o.w = (unsigned)f2bf_rne(b.z) | ((unsigned)f2bf_rne(b.w) << 16);
  }
  int key = (n * 204 + pi) & 7;               // absolute padded-row parity
  long long pos = ((long long)(n * 204 + pi)) * 256 + (c8 ^ key);
  *(uint4*)(out + pos * 8) = o;
}

// ---------------- zero the pad rows of a padded [n][rpad][cin] bf16 tensor ----------------
__global__ void k_zero_pad(u16* __restrict__ p, int ncnt, int rpad, int lr, int P,
                           int cin8, int total) {
  int idx = blockIdx.x * 256 + threadIdx.x;
  if (idx >= total) return;
  int c = idx % cin8;
  int pr = (idx / cin8) % (rpad - lr);
  int n = idx / (cin8 * (rpad - lr));
  int row = (pr < P) ? pr : lr + pr;
  *(uint4*)(p + ((long long)(n * rpad + row) * cin8 + c) * 8) = make_uint4(0, 0, 0, 0);
}

// ---------------- generic fp32 -> bf16 cast ----------------
__global__ void k_cast_bf16(const float* __restrict__ in, u16* __restrict__ out, int n8) {
  int idx = blockIdx.x * 256 + threadIdx.x;
  if (idx >= n8) return;
  const float4* p = (const float4*)in + (long long)idx * 2;
  float4 a = p[0], b = p[1];
  uint4 o;
  o.x = (unsigned)f2bf_rne(a.x) | ((unsigned)f2bf_rne(a.y) << 16);
  o.y = (unsigned)f2bf_rne(a.z) | ((unsigned)f2bf_rne(a.w) << 16);
  o.z = (unsigned)f2bf_rne(b.x) | ((unsigned)f2bf_rne(b.y) << 16);
  o.w = (unsigned)f2bf_rne(b.z) | ((unsigned)f2bf_rne(b.w) << 16);
  *(uint4*)(out + (long long)idx * 8) = o;
}

// conv weight [co][ci][t] -> [co][t][ci]  (= B[N][K], K = 5*Cin)
__global__ void k_conv_w_t(const float* __restrict__ in, u16* __restrict__ out,
                           int Cout, int Cin, int Kk) {
  int idx = blockIdx.x * 256 + threadIdx.x;
  int total = Cout * Cin * Kk;
  if (idx >= total) return;
  int ci = idx % Cin;
  int t  = (idx / Cin) % Kk;
  int co = idx / (Cin * Kk);
  out[idx] = f2bf_rne(in[(co * Cin + ci) * Kk + t]);
}

// deconv weight [ci][co][4] -> per-parity conv weights [z][co][tt][ci], t = 3 - z - 2*tt
__global__ void k_deconv_w_par(const float* __restrict__ in, u16* __restrict__ out,
                               int Cin, int Cout) {
  int idx = blockIdx.x * 256 + threadIdx.x;
  int total = Cin * Cout * 4;
  if (idx >= total) return;
  int ci = idx % Cin;
  int tt = (idx / Cin) & 1;
  int co = (idx / (2 * Cin)) % Cout;
  int zz = idx / (2 * Cin * Cout);
  out[idx] = f2bf_rne(in[(ci * Cout + co) * 4 + 3 - zz - 2 * tt]);
}

// ---------------- small precompute: q[z][b][c], v[z][b][c] ----------------
__global__ __launch_bounds__(256) void k_prep_small(
    const float* __restrict__ concept1, const float* __restrict__ concept2,
    const float* __restrict__ w_ca1, const float* __restrict__ w_sim1,
    const float* __restrict__ w_sim2, const float* __restrict__ w_mlp,
    float* __restrict__ qv) {
  int cz = blockIdx.x >> 2;
  int b  = blockIdx.x & 3;
  const float* con = cz ? concept2 : concept1;
  __shared__ float cvec[CDIM];
  __shared__ float chat[SDIM];
  int tid = threadIdx.x;
  for (int j = tid; j < CDIM; j += 256) cvec[j] = con[b * CDIM + j];
  __syncthreads();
  float accq = 0.f;
  for (int j = 0; j < CDIM; ++j) accq += cvec[j] * w_ca1[tid * CDIM + j];
  qv[(cz * 4 + b) * 256 + tid] = accq;
  for (int i = 0; i < 4; ++i) {
    int s = tid + i * 256;
    float a2 = 0.f;
    for (int j = 0; j < CDIM; ++j) a2 += cvec[j] * w_sim2[s * CDIM + j];
    chat[s] = a2 * w_mlp[s];
  }
  __syncthreads();
  float v = 0.f;
  for (int s = 0; s < SDIM; ++s) v += w_sim1[s * 256 + tid] * chat[s];
  qv[2048 + (cz * 4 + b) * 256 + tid] = v;
}

// ======================= conv1 GEMM: 256x128 tile, 8 waves, A-dedup =======================
// Same verified structure as k_gemm_conv (A staged once per ci-block across all 5
// taps; XOR-swizzled row-major A tile; frag-order B; tap-inner chunks; counted
// vmcnt), but 256 output rows per block -> row-tiles 125 -> 63, halving B staging
// (the post-R3 dominant staged-byte term). 512 threads = 8 waves (4M x 2N of
// 64x64 sub-tiles). Per chunk each wave issues exactly 1 A-piece + 2 B-frags ->
// steady wait vmcnt(3) (this chunk's issues stay in flight across both barriers).
// A tile: [320][64] bf16 x2 buf (needs <=268 rows = 260+4*nc, staged 320 with
// tail clamp; clamped rows only feed masked outputs). LDS 112 KB -> 1 block/CU.
__global__ __launch_bounds__(512) void k_gemm_conv1(
    const u16* __restrict__ A, const u16* __restrict__ Bw,
    u16* __restrict__ Co, const float* __restrict__ bias,
    int M, int N, int Ktot, int cin, int ncib,
    int lr, int rpad, int px, int yspan, int gy,
    int orpad, int ooff, long long aend) {
  __shared__ __align__(16) u16 At[2][20480];   // [2][320][64]
  __shared__ __align__(16) u16 Bs[2][8192];    // [2][16 frags][512]
  int id = blockIdx.x;
  int k8 = id & 7, j = id >> 3;
  int x = k8 / px, h = k8 - x * px;
  int y = h * yspan + j;
  if (y >= gy) return;
  int row0 = y * 256, col0 = x * 128;
  int tid = threadIdx.x, w = tid >> 6, ln = tid & 63;
  int r15 = ln & 15, q = ln >> 4;

  // contiguous A prow range for this tile
  int n0 = row0 / lr, l0 = row0 - n0 * lr;
  long long prow0 = (long long)n0 * rpad + l0;

  // per-lane per-mi A read bases: row_local = rlb + t, parity = (pp + t)&7
  int wrb = (w >> 1) * 64;
  int rlb[4], pp[4];
  #pragma unroll
  for (int mi = 0; mi < 4; ++mi) {
    int rr = wrb + mi * 16 + r15;
    int nc = (row0 + rr) / lr - n0;          // n-boundaries crossed (0..2)
    rlb[mi] = rr + 4 * nc;
    pp[mi] = (int)((prow0 + rlb[mi]) & 7);
  }

  // A staging: wave w stages rows [w*40, w*40+40) in 5 pieces of 8 rows.
  long long arow_base = prow0 + w * 40 + (ln >> 3);
  const u16* alim = A + (aend - 8);
  auto stA = [&](int cib_, int pc) {
    const u16* src = A + (arow_base + pc * 8) * cin + cib_ * 64 + (ln & 7) * 8;
    if (src > alim) src = alim;              // clamp tail-tile overrun (rows unused)
    gload16(src, At[cib_ & 1] + (w * 40 + pc * 8) * 64);
  };

  // B staging: wave w stages both ks of col-16-block w (frags 2w, 2w+1)
  const u16* gb[2];
  #pragma unroll
  for (int i = 0; i < 2; ++i) {
    int klocal = i * 32 + q * 8;
    int br = col0 + w * 16 + r15;
    gb[i] = Bw + ((long long)br * Ktot + klocal);
  }

  f32x4 acc[4][4];
  #pragma unroll
  for (int i = 0; i < 4; ++i)
    #pragma unroll
    for (int j2 = 0; j2 < 4; ++j2) acc[i][j2] = (f32x4){0.f, 0.f, 0.f, 0.f};
  int wc2 = (w & 1) * 4;

  // prologue: A(cib=0) all 5 pieces + B(chunk 0); drain; barrier
  #pragma unroll
  for (int pc = 0; pc < 5; ++pc) stA(0, pc);
  #pragma unroll
  for (int i = 0; i < 2; ++i) gload16(gb[i], Bs[0] + (2 * w + i) * 512);
  #pragma unroll
  for (int i = 0; i < 2; ++i) gb[i] += cin;  // advance to chunk 1 (tap0 -> tap1)
  int ts = 1;                                 // tap of next chunk to stage
  asm volatile("s_waitcnt vmcnt(0)" ::: "memory");
  __builtin_amdgcn_s_barrier();

  long long bwrap = 64 - 4 * (long long)cin;
  for (int cib = 0; cib < ncib; ++cib) {
    bool lastcib = (cib == ncib - 1);
    #pragma unroll
    for (int t = 0; t < 5; ++t) {
      bool lastc = lastcib && (t == 4);
      // issue prefetches: A-piece of cib+1 FIRST, then B of chunk c+1
      if (!lastcib) stA(cib + 1, t);
      if (!lastc) {
        int bufn = (cib + t + 1) & 1;        // chunk index = cib*5+t; 5 odd -> cib+t parity
        #pragma unroll
        for (int i = 0; i < 2; ++i) gload16(gb[i], Bs[bufn] + (2 * w + i) * 512);
        long long d = (ts == 4) ? bwrap : (long long)cin;
        ts = (ts == 4) ? 0 : ts + 1;
        #pragma unroll
        for (int i = 0; i < 2; ++i) gb[i] += d;
      }
      if (lastc)        asm volatile("s_waitcnt vmcnt(0)" ::: "memory");
      else if (lastcib) asm volatile("s_waitcnt vmcnt(2)" ::: "memory");
      else              asm volatile("s_waitcnt vmcnt(3)" ::: "memory");
      __builtin_amdgcn_s_barrier();            // buf ready for all waves
      __builtin_amdgcn_sched_barrier(0);
      // compute chunk (cib, t)
      const u16* Ab = At[cib & 1];
      const u16* Bb = Bs[(cib + t) & 1];
      int rof[4], pr8[4];
      #pragma unroll
      for (int mi = 0; mi < 4; ++mi) {
        rof[mi] = (rlb[mi] + t) * 64;
        pr8[mi] = (pp[mi] + t) & 7;
      }
      #pragma unroll
      for (int ks = 0; ks < 2; ++ks) {
        bf16x8 af[4], bf[4];
        #pragma unroll
        for (int mi = 0; mi < 4; ++mi)
          af[mi] = *(const bf16x8*)&Ab[rof[mi] + (((ks * 4 + q) ^ pr8[mi]) * 8)];
        #pragma unroll
        for (int ni = 0; ni < 4; ++ni)
          bf[ni] = *(const bf16x8*)&Bb[(((wc2 + ni) * 2 + ks) * 512) + ln * 8];
        #pragma unroll
        for (int mi = 0; mi < 4; ++mi)
          #pragma unroll
          for (int ni = 0; ni < 4; ++ni)
            acc[mi][ni] = __builtin_amdgcn_mfma_f32_16x16x32_bf16(
                af[mi], bf[ni], acc[mi][ni], 0, 0, 0);
      }
      __builtin_amdgcn_sched_barrier(0);
      __builtin_amdgcn_s_barrier();            // reads done before next overwrite
    }
  }

  // epilogue: maxpool2 + bias -> bf16 [n][orpad][N], col-swizzled (feeds conv2)
  int q4 = q * 4;
  int wrow = (w >> 1) * 64, wcol = (w & 1) * 64;
  int lrh = lr >> 1;
  #pragma unroll
  for (int mi = 0; mi < 4; ++mi) {
    int gbase = row0 + wrow + mi * 16 + q4;
    #pragma unroll
    for (int p = 0; p < 2; ++p) {
      int grow = gbase + 2 * p;
      if (grow < M) {
        int prow = grow >> 1;
        int n = prow / lrh, ll = prow - n * lrh;
        long long orow = (long long)n * orpad + ooff + ll;
        int key = (int)(orow & 7) << 3;
        #pragma unroll
        for (int ni = 0; ni < 4; ++ni) {
          int col = col0 + wcol + ni * 16 + r15;
          float v = fmaxf(acc[mi][ni][2 * p], acc[mi][ni][2 * p + 1]) + bias[col];
          Co[orow * N + (col ^ key)] = f2bf_rne(v);
        }
      }
    }
  }
}

// ======================= conv GEMM with A-dedup (128-row tile) =======================
// Used for conv2. See R3 notes: A staged once per 64-ci block into a [160][64]
// XOR-swizzled row-major tile; frag-order B; tap-inner chunks; per wave per chunk
// 1 A-piece + 4 B-frags, counted vmcnt(5)/(4)/(0); double-buffered.
template <int SWZO>
__global__ __launch_bounds__(256) void k_gemm_conv(
    const u16* __restrict__ A, const u16* __restrict__ Bw,
    u16* __restrict__ Co, const float* __restrict__ bias,
    int M, int N, int Ktot, int cin, int ncib,
    int lr, int rpad, int px, int yspan, int gy,
    int orpad, int ooff, long long aend) {
  __shared__ __align__(16) u16 At[2][10240];   // [2][160][64]
  __shared__ __align__(16) u16 Bs[2][8192];
  int id = blockIdx.x;
  int k8 = id & 7, j = id >> 3;
  int x = k8 / px, h = k8 - x * px;
  int y = h * yspan + j;
  if (y >= gy) return;
  int row0 = y * 128, col0 = x * 128;
  int tid = threadIdx.x, w = tid >> 6, ln = tid & 63;
  int r15 = ln & 15, q = ln >> 4;

  int n0 = row0 / lr, l0 = row0 - n0 * lr;
  long long prow0 = (long long)n0 * rpad + l0;

  int wrb = (w >> 1) * 64;
  int rlb[4], pp[4];
  #pragma unroll
  for (int mi = 0; mi < 4; ++mi) {
    int rr = wrb + mi * 16 + r15;
    int nc = (row0 + rr) / lr - n0;
    rlb[mi] = rr + 4 * nc;
    pp[mi] = (int)((prow0 + rlb[mi]) & 7);
  }

  long long arow_base = prow0 + w * 40 + (ln >> 3);
  const u16* alim = A + (aend - 8);
  auto stA = [&](int cib_, int pc) {
    const u16* src = A + (arow_base + pc * 8) * cin + cib_ * 64 + (ln & 7) * 8;
    if (src > alim) src = alim;
    gload16(src, At[cib_ & 1] + (w * 40 + pc * 8) * 64);
  };

  const u16* gb[4];
  #pragma unroll
  for (int i = 0; i < 4; ++i) {
    int f = 4 * w + i, blk = f >> 1, ks = f & 1;
    int klocal = ks * 32 + q * 8;
    int br = col0 + blk * 16 + r15;
    gb[i] = Bw + ((long long)br * Ktot + klocal);
  }
  int wbase = 4 * w * 512;

  f32x4 acc[4][4];
  #pragma unroll
  for (int i = 0; i < 4; ++i)
    #pragma unroll
    for (int j2 = 0; j2 < 4; ++j2) acc[i][j2] = (f32x4){0.f, 0.f, 0.f, 0.f};
  int wc2 = (w & 1) * 4;

  #pragma unroll
  for (int pc = 0; pc < 5; ++pc) stA(0, pc);
  #pragma unroll
  for (int i = 0; i < 4; ++i) gload16(gb[i], Bs[0] + wbase + i * 512);
  #pragma unroll
  for (int i = 0; i < 4; ++i) gb[i] += cin;
  int ts = 1;
  asm volatile("s_waitcnt vmcnt(0)" ::: "memory");
  __builtin_amdgcn_s_barrier();

  long long bwrap = 64 - 4 * (long long)cin;
  for (int cib = 0; cib < ncib; ++cib) {
    bool lastcib = (cib == ncib - 1);
    #pragma unroll
    for (int t = 0; t < 5; ++t) {
      bool lastc = lastcib && (t == 4);
      if (!lastcib) stA(cib + 1, t);
      if (!lastc) {
        int bufn = (cib + t + 1) & 1;
        #pragma unroll
        for (int i = 0; i < 4; ++i) gload16(gb[i], Bs[bufn] + wbase + i * 512);
        long long d = (ts == 4) ? bwrap : (long long)cin;
        ts = (ts == 4) ? 0 : ts + 1;
        #pragma unroll
        for (int i = 0; i < 4; ++i) gb[i] += d;
      }
      if (lastc)        asm volatile("s_waitcnt vmcnt(0)" ::: "memory");
      else if (lastcib) asm volatile("s_waitcnt vmcnt(4)" ::: "memory");
      else              asm volatile("s_waitcnt vmcnt(5)" ::: "memory");
      __builtin_amdgcn_s_barrier();
      __builtin_amdgcn_sched_barrier(0);
      const u16* Ab = At[cib & 1];
      const u16* Bb = Bs[(cib + t) & 1];
      int rof[4], pr8[4];
      #pragma unroll
      for (int mi = 0; mi < 4; ++mi) {
        rof[mi] = (rlb[mi] + t) * 64;
        pr8[mi] = (pp[mi] + t) & 7;
      }
      #pragma unroll
      for (int ks = 0; ks < 2; ++ks) {
        bf16x8 af[4], bf[4];
        #pragma unroll
        for (int mi = 0; mi < 4; ++mi)
          af[mi] = *(const bf16x8*)&Ab[rof[mi] + (((ks * 4 + q) ^ pr8[mi]) * 8)];
        #pragma unroll
        for (int ni = 0; ni < 4; ++ni)
          bf[ni] = *(const bf16x8*)&Bb[(((wc2 + ni) * 2 + ks) * 512) + ln * 8];
        #pragma unroll
        for (int mi = 0; mi < 4; ++mi)
          #pragma unroll
          for (int ni = 0; ni < 4; ++ni)
            acc[mi][ni] = __builtin_amdgcn_mfma_f32_16x16x32_bf16(
                af[mi], bf[ni], acc[mi][ni], 0, 0, 0);
      }
      __builtin_amdgcn_sched_barrier(0);
      __builtin_amdgcn_s_barrier();
    }
  }

  int q4 = q * 4;
  int wrow = (w >> 1) * 64, wcol = (w & 1) * 64;
  int lrh = lr >> 1;
  #pragma unroll
  for (int mi = 0; mi < 4; ++mi) {
    int gbase = row0 + wrow + mi * 16 + q4;
    #pragma unroll
    for (int p = 0; p < 2; ++p) {
      int grow = gbase + 2 * p;
      if (grow < M) {
        int prow = grow >> 1;
        int n = prow / lrh, ll = prow - n * lrh;
        long long orow = (long long)n * orpad + ooff + ll;
        int key = SWZO ? ((int)(orow & 7) << 3) : 0;
        #pragma unroll
        for (int ni = 0; ni < 4; ++ni) {
          int col = col0 + wcol + ni * 16 + r15;
          float v = fmaxf(acc[mi][ni][2 * p], acc[mi][ni][2 * p + 1]) + bias[col];
          Co[orow * N + (col ^ key)] = f2bf_rne(v);
        }
      }
    }
  }
}

// ---------------- generic bf16-MFMA NT GEMM (kproj, deconvs) ----------------
#define EP_PLAIN 0
#define EP_POOL  1
#define EP_ILV   2

template <int EP>
__global__ __launch_bounds__(256) void k_gemm(
    const u16* __restrict__ A, const u16* __restrict__ Bw,
    void* __restrict__ Co, const float* __restrict__ bias,
    int M, int N, int Ktot, int nchunk,
    int lr, int rpad, int cin, int off0c, int taps,
    int px, int yspan, int gy, long long sB, int orpad, int ooff) {
  __shared__ __align__(16) u16 As[2][8192];
  __shared__ __align__(16) u16 Bs[2][8192];
  int id = blockIdx.x;
  int k8 = id & 7, j = id >> 3;
  int x = k8 / px, h = k8 - x * px;
  int y = h * yspan + j;
  if (y >= gy) return;
  int z = blockIdx.z;
  int off0 = (EP == EP_ILV) ? z : off0c;
  int row0 = y * 128, col0 = x * 128;
  int tid = threadIdx.x, w = tid >> 6, ln = tid & 63;
  const u16* Bz = Bw + (long long)z * sB;

  const u16* ga[4];
  const u16* gb[4];
  #pragma unroll
  for (int i = 0; i < 4; ++i) {
    int f = 4 * w + i, blk = f >> 1, ks = f & 1;
    int klocal = ks * 32 + (ln >> 4) * 8;
    int ar = row0 + blk * 16 + (ln & 15);
    int n_ = ar / lr, l_ = ar - n_ * lr;
    ga[i] = A + ((long long)(n_ * rpad + l_ + off0) * cin + klocal);
    int br = col0 + blk * 16 + (ln & 15);
    gb[i] = Bz + ((long long)br * Ktot + klocal);
  }
  int wbase = 4 * w * 512;

  f32x4 acc[4][4];
  #pragma unroll
  for (int i = 0; i < 4; ++i)
    #pragma unroll
    for (int j2 = 0; j2 < 4; ++j2) acc[i][j2] = (f32x4){0.f, 0.f, 0.f, 0.f};

  int wr2 = (w >> 1) * 4;
  int wc2 = (w & 1) * 4;

  long long dstep = cin;
  long long dwrap = 64 - (long long)(taps - 1) * cin;
  int tc = 0;

  #pragma unroll
  for (int i = 0; i < 4; ++i) {
    gload16(ga[i], As[0] + wbase + i * 512);
    gload16(gb[i], Bs[0] + wbase + i * 512);
  }
  {
    long long d = (tc == taps - 1) ? dwrap : dstep;
    tc = (tc == taps - 1) ? 0 : tc + 1;
    #pragma unroll
    for (int i = 0; i < 4; ++i) { ga[i] += d; gb[i] += d; }
  }

  for (int c = 0; c < nchunk; ++c) {
    int cur = c & 1;
    if (c + 1 < nchunk) {
      u16* dA = As[cur ^ 1] + wbase;
      u16* dB = Bs[cur ^ 1] + wbase;
      #pragma unroll
      for (int i = 0; i < 4; ++i) {
        gload16(ga[i], dA + i * 512);
        gload16(gb[i], dB + i * 512);
      }
      long long d = (tc == taps - 1) ? dwrap : dstep;
      tc = (tc == taps - 1) ? 0 : tc + 1;
      #pragma unroll
      for (int i = 0; i < 4; ++i) { ga[i] += d; gb[i] += d; }
      asm volatile("s_waitcnt vmcnt(8)" ::: "memory");
    } else {
      asm volatile("s_waitcnt vmcnt(0)" ::: "memory");
    }
    __builtin_amdgcn_s_barrier();
    __builtin_amdgcn_sched_barrier(0);
    #pragma unroll
    for (int ks = 0; ks < 2; ++ks) {
      bf16x8 af[4], bf[4];
      #pragma unroll
      for (int mi = 0; mi < 4; ++mi)
        af[mi] = *(const bf16x8*)&As[cur][(((wr2 + mi) * 2 + ks) * 512) + ln * 8];
      #pragma unroll
      for (int ni = 0; ni < 4; ++ni)
        bf[ni] = *(const bf16x8*)&Bs[cur][(((wc2 + ni) * 2 + ks) * 512) + ln * 8];
      #pragma unroll
      for (int mi = 0; mi < 4; ++mi)
        #pragma unroll
        for (int ni = 0; ni < 4; ++ni)
          acc[mi][ni] = __builtin_amdgcn_mfma_f32_16x16x32_bf16(
              af[mi], bf[ni], acc[mi][ni], 0, 0, 0);
    }
    __builtin_amdgcn_sched_barrier(0);
    __builtin_amdgcn_s_barrier();
  }

  int c15 = ln & 15, q4 = (ln >> 4) * 4;
  int wrow = (w >> 1) * 64, wcol = (w & 1) * 64;
  if (EP == EP_PLAIN) {
    float* Cz = (float*)Co;
    #pragma unroll
    for (int mi = 0; mi < 4; ++mi) {
      int gbase = row0 + wrow + mi * 16 + q4;
      #pragma unroll
      for (int r = 0; r < 4; ++r) {
        int grow = gbase + r;
        if (grow < M) {
          #pragma unroll
          for (int ni = 0; ni < 4; ++ni) {
            int col = col0 + wcol + ni * 16 + c15;
            Cz[(long long)grow * N + col] = acc[mi][ni][r];
          }
        }
      }
    }
  } else if (EP == EP_POOL) {
    u16* Cz = (u16*)Co;
    int lrh = lr >> 1;
    #pragma unroll
    for (int mi = 0; mi < 4; ++mi) {
      int gbase = row0 + wrow + mi * 16 + q4;
      #pragma unroll
      for (int p = 0; p < 2; ++p) {
        int grow = gbase + 2 * p;
        if (grow < M) {
          int prow = grow >> 1;
          int n = prow / lrh, ll = prow - n * lrh;
          long long orow = (long long)n * orpad + ooff + ll;
          #pragma unroll
          for (int ni = 0; ni < 4; ++ni) {
            int col = col0 + wcol + ni * 16 + c15;
            float v = fmaxf(acc[mi][ni][2 * p], acc[mi][ni][2 * p + 1]) + bias[col];
            Cz[orow * N + col] = f2bf_rne(v);
          }
        }
      }
    }
  } else {  // EP_ILV
    u16* Cz = (u16*)Co;
    #pragma unroll
    for (int mi = 0; mi < 4; ++mi) {
      int gbase = row0 + wrow + mi * 16 + q4;
      #pragma unroll
      for (int r = 0; r < 4; ++r) {
        int grow = gbase + r;
        if (grow < M) {
          int n = grow / lr, l = grow - n * lr;
          long long orow = (long long)n * orpad + ooff + 2 * l + z;
          #pragma unroll
          for (int ni = 0; ni < 4; ++ni) {
            int col = col0 + wcol + ni * 16 + c15;
            Cz[orow * N + col] = f2bf_rne(acc[mi][ni][r] + bias[col]);
          }
        }
      }
    }
  }
}

// ---------------- attention: wave-parallel scores + softmax + weighted sum ----------------
__global__ __launch_bounds__(256) void k_attention(
    const float* __restrict__ kproj, const u16* __restrict__ t2b,
    const float* __restrict__ qv, const float* __restrict__ w_ca3,
    const int* __restrict__ seg_len, u16* __restrict__ rb) {
  int bm = blockIdx.x % BM;
  int cz = blockIdx.x / BM;
  int b = bm / MM;
  int tid = threadIdx.x, w = tid >> 6, ln = tid & 63;
  __shared__ float sq[256], sw[256], sa[L4 + 14];
  sq[tid] = qv[(cz * 4 + b) * 256 + tid];
  sw[tid] = w_ca3[tid];
  __syncthreads();
  int kmax = (seg_len[bm] + 3) >> 2;
  for (int k = w; k < L4; k += 4) {
    float val = 0.f;
    #pragma unroll
    for (int i = 0; i < 4; ++i) {
      int c = ln + 64 * i;
      val += tanhf(sq[c] + kproj[(bm * L4 + k) * 256 + c]) * sw[c];
    }
    for (int off = 32; off > 0; off >>= 1) val += __shfl_down(val, off, 64);
    if (ln == 0) sa[k] = (k < kmax) ? val : -1e15f;
  }
  __syncthreads();
  if (w == 0) {
    float sv = (ln < L4) ? sa[ln] : -3e38f;
    float mx = sv;
    for (int off = 32; off > 0; off >>= 1) mx = fmaxf(mx, __shfl_down(mx, off, 64));
    mx = __shfl(mx, 0, 64);
    float e = (ln < L4) ? expf(sv - mx) : 0.f;
    float s = e;
    for (int off = 32; off > 0; off >>= 1) s += __shfl_down(s, off, 64);
    s = __shfl(s, 0, 64);
    if (ln < L4) sa[ln] = e / s;
  }
  __syncthreads();
  float r = 0.f;
  for (int k = 0; k < L4; ++k) r += sa[k] * bf2f(t2b[(bm * L4 + k) * 256 + tid]);
  rb[(cz * BM + bm) * 256 + tid] = f2bf_rne(r);
}

// ---------------- build cat matrix, padded [80][52][768] bf16, interior rows 1..50 ----------------
__global__ void k_build_cat(const u16* __restrict__ t2b, const u16* __restrict__ rb,
                            u16* __restrict__ catm, int total) {
  int idx = blockIdx.x * 256 + threadIdx.x;
  if (idx >= total) return;
  int ci = idx % 768;
  int row = idx / 768;        // bm*50 + li
  int bm = row / L4, li = row - bm * L4;
  u16 v;
  if (ci < 256)      v = t2b[row * 256 + ci];
  else if (ci < 512) v = rb[bm * 256 + (ci - 256)];
  else               v = rb[(BM + bm) * 256 + (ci - 512)];
  catm[((long long)(bm * 52 + 1 + li)) * 768 + ci] = v;
}

// ---------------- final projection + sigmoid (reads bf16 d2) ----------------
__global__ __launch_bounds__(256) void k_final(
    const u16* __restrict__ d2b, const float* __restrict__ qv,
    const float* __restrict__ b_mlp, float* __restrict__ out) {
  int row = blockIdx.x;          // n*200 + lo
  int n = row / LL, lo = row % LL;
  int b = n / MM, m = n % MM;
  int tid = threadIdx.x;
  float v = bf2f(d2b[(long long)row * 256 + tid]);
  float p1 = v * qv[2048 + (0 * 4 + b) * 256 + tid];
  float p2 = v * qv[2048 + (1 * 4 + b) * 256 + tid];
  for (int off = 32; off > 0; off >>= 1) {
    p1 += __shfl_down(p1, off, 64);
    p2 += __shfl_down(p2, off, 64);
  }
  __shared__ float s1[4], s2[4];
  if ((tid & 63) == 0) { s1[tid >> 6] = p1; s2[tid >> 6] = p2; }
  __syncthreads();
  if (tid == 0) {
    float bmlp = b_mlp[0];
    float a1 = s1[0] + s1[1] + s1[2] + s1[3] + bmlp;
    float a2 = s2[0] + s2[1] + s2[2] + s2[3] + bmlp;
    int t_idx = m * LL + lo;
    out[b * 4000 + t_idx]         = 1.f / (1.f + expf(-a1));
    out[16000 + b * 4000 + t_idx] = 1.f / (1.f + expf(-a2));
  }
}

// ---------------- host ----------------
extern "C" void kernel_launch(void* const* d_in, const int* in_sizes, int n_in,
                              void* d_out, int out_size, void* d_ws, size_t ws_size,
                              hipStream_t stream) {
  const float* batch    = (const float*)d_in[0];
  const int*   seg_len  = (const int*)d_in[1];
  const float* concept1 = (const float*)d_in[2];
  const float* concept2 = (const float*)d_in[3];
  const float* w_conv1  = (const float*)d_in[4];
  const float* b_conv1  = (const float*)d_in[5];
  const float* w_conv2  = (const float*)d_in[6];
  const float* b_conv2  = (const float*)d_in[7];
  const float* w_ca1    = (const float*)d_in[8];
  const float* w_ca2    = (const float*)d_in[9];
  const float* w_ca3    = (const float*)d_in[10];
  const float* w_dc1    = (const float*)d_in[11];
  const float* b_dc1    = (const float*)d_in[12];
  const float* w_dc2    = (const float*)d_in[13];
  const float* b_dc2    = (const float*)d_in[14];
  const float* w_sim1   = (const float*)d_in[15];
  const float* w_sim2   = (const float*)d_in[16];
  const float* w_mlp    = (const float*)d_in[17];
  const float* b_mlp    = (const float*)d_in[18];
  float* out = (float*)d_out;

  float* ws = (float*)d_ws;
  // workspace (float units) — total 24,477,696 f = 97.9 MB
  const long long off_qv    = 0;          //      4,096
  const long long off_kproj = 4096;       //  1,024,000 fp32
  const long long off_rb    = 1028096;    //     20,480 (u16 40,960)
  const long long off_t1    = 1048576;    //  2,162,688 (t1b [80][104][512]+slack)
  const long long off_t2    = 3211264;    //    524,288 (t2b [4000][256]+slack)
  const long long off_w1b   = 3735552;    //  2,621,440
  const long long off_w2b   = 6356992;    //    327,680
  const long long off_wd1p  = 6684672;    //    786,432
  const long long off_wd2p  = 7471104;    //    262,144
  const long long off_wca2b = 7733248;    //     32,768
  const long long off_BIG   = 7766016;    // 16,711,680 (batchb -> catm/d1b/d2b)

  u16* rb    = (u16*)(ws + off_rb);
  u16* t1b   = (u16*)(ws + off_t1);
  u16* t2b   = (u16*)(ws + off_t2);
  u16* w1b   = (u16*)(ws + off_w1b);
  u16* w2b   = (u16*)(ws + off_w2b);
  u16* wd1p  = (u16*)(ws + off_wd1p);
  u16* wd2p  = (u16*)(ws + off_wd2p);
  u16* wca2b = (u16*)(ws + off_wca2b);
  u16* batchb = (u16*)(ws + off_BIG);               // [80][204][2048] swizzled
  u16* catm   = (u16*)(ws + off_BIG);               // [80][52][768]+slack (after conv1)
  u16* d1b    = (u16*)(ws + off_BIG) + 3342336;     // [80][102][512]+slack
  u16* d2b    = (u16*)(ws + off_BIG) + 7667712;     // [16000][256]

  // --- prep: padded+swizzled bf16 batch, bf16 weights, small vectors ---
  k_cast_pad_batch<<<dim3(16320), 256, 0, stream>>>(batch, batchb);
  k_conv_w_t<<<dim3(20480), 256, 0, stream>>>(w_conv1, w1b, C1, INC, 5);
  k_conv_w_t<<<dim3(2560), 256, 0, stream>>>(w_conv2, w2b, C2, C1, 5);
  k_deconv_w_par<<<dim3(6144), 256, 0, stream>>>(w_dc1, wd1p, 3 * C2, DC1);
  k_deconv_w_par<<<dim3(2048), 256, 0, stream>>>(w_dc2, wd2p, DC1, DC2);
  k_cast_bf16<<<dim3(32), 256, 0, stream>>>(w_ca2, wca2b, 8192);
  k_prep_small<<<dim3(8), 256, 0, stream>>>(concept1, concept2, w_ca1, w_sim1, w_sim2,
                                            w_mlp, ws + off_qv);
  k_zero_pad<<<dim3(80), 256, 0, stream>>>(t1b, 80, 104, 100, 2, 64, 20480);

  // --- conv1 + pool + bias -> t1b [80][104][512] SWIZZLED (M=16000,N=512,K=10240)
  // 256x128 tile, 8 waves; gx=4 -> px=2, yspan=32, grid 8*32=256; ncib=32
  k_gemm_conv1<<<dim3(256), 512, 0, stream>>>(
      batchb, w1b, t1b, b_conv1, 16000, 512, 10240, 2048, 32,
      200, 204, 2, 32, 63, 104, 2, 80LL * 204 * 2048);

  // batchb dead -> zero pads of catm / d1b (they overlay it)
  k_zero_pad<<<dim3(60), 256, 0, stream>>>(catm, 80, 52, 50, 1, 96, 15360);
  k_zero_pad<<<dim3(40), 256, 0, stream>>>(d1b, 80, 102, 100, 1, 64, 10240);

  // --- conv2 + pool + bias -> t2b [4000][256] plain (M=8000,N=256,K=2560)
  // ncib = 512/64 = 8; gx=2 -> px=4, yspan=16, grid 128
  k_gemm_conv<0><<<dim3(128), 256, 0, stream>>>(
      t1b, w2b, t2b, b_conv2, 8000, 256, 2560, 512, 8,
      100, 104, 4, 16, 63, 50, 0, 80LL * 104 * 512);

  // --- kproj = t2 @ w_ca2^T -> fp32 [4000][256] (M=4000,N=256,K=256)
  k_gemm<EP_PLAIN><<<dim3(64), 256, 0, stream>>>(
      t2b, wca2b, ws + off_kproj, nullptr, 4000, 256, 256, 4,
      4000, 4000, 256, 0, 1, 4, 8, 32, 0, 0, 0);

  // --- attention -> rb bf16 [2][80][256]
  k_attention<<<dim3(160), 256, 0, stream>>>(ws + off_kproj, t2b, ws + off_qv,
                                             w_ca3, seg_len, rb);

  // --- cat -> catm padded [80][52][768]
  k_build_cat<<<dim3(12000), 256, 0, stream>>>(t2b, rb, catm, 4000 * 768);

  // --- deconv1: 2 parity convs + bias -> d1b [80][102][512] (M=4000,N=512,K=1536)
  k_gemm<EP_ILV><<<dim3(128, 1, 2), 256, 0, stream>>>(
      catm, wd1p, d1b, b_dc1, 4000, 512, 1536, 24,
      50, 52, 768, 0, 2, 2, 16, 32, 786432LL, 102, 1);

  // --- deconv2: 2 parity convs + bias -> d2b [16000][256] (M=8000,N=256,K=1024)
  k_gemm<EP_ILV><<<dim3(128, 1, 2), 256, 0, stream>>>(
      d1b, wd2p, d2b, b_dc2, 8000, 256, 1024, 16,
      100, 102, 512, 0, 2, 4, 16, 63, 262144LL, 200, 0);

  // --- final dot + sigmoid -> out (sc1 | sc2) fp32
  k_final<<<dim3(16000), 256, 0, stream>>>(d2b, ws + off_qv, b_mlp, out);
}

// Round 5
// 733.635 us; speedup vs baseline: 1.0478x; 1.0478x over previous
//
#include <hip/hip_runtime.h>
#include <hip/hip_bf16.h>
#include <math.h>

// Problem constants
#define BB 4
#define MM 20
#define LL 200
#define INC 2048
#define C1 512
#define C2 256
#define CDIM 300
#define DC1 512
#define DC2 256
#define SDIM 1024
#define BM 80           // B*M
#define L2 100          // L/2
#define L4 50           // L/4

typedef unsigned short u16;
typedef __attribute__((ext_vector_type(8))) short bf16x8;
typedef __attribute__((ext_vector_type(4))) float f32x4;

__device__ __forceinline__ u16 f2bf_rne(float f) {
  unsigned u = __float_as_uint(f);
  unsigned r = u + 0x7FFFu + ((u >> 16) & 1u);
  return (u16)(r >> 16);
}
__device__ __forceinline__ float bf2f(u16 v) {
  return __uint_as_float(((unsigned)v) << 16);
}

// async global -> LDS, 16 B per lane. LDS dest = wave-uniform base + lane*16.
// Global SOURCE is per-lane (arbitrary); dest is linear.
__device__ __forceinline__ void gload16(const u16* g, u16* l) {
  __builtin_amdgcn_global_load_lds(
      (const __attribute__((address_space(1))) void*)g,
      (__attribute__((address_space(3))) void*)l, 16, 0, 0);
}

// ---------------- batch fp32 -> bf16, 2-row zero pad, GLOBAL XOR-SWIZZLE ----------------
// Layout [80][204][2048] bf16; within each (prow, 64-ci block) the 16B unit u is
// stored at u ^ (prow&7). Consumed by the conv GEMMs' row-major A tiles
// (linear gload_lds dest + pre-swizzled source + XOR on read).
__global__ void k_cast_pad_batch(const float* __restrict__ in, u16* __restrict__ out) {
  int idx = blockIdx.x * 256 + threadIdx.x;   // octet index
  if (idx >= 80 * 204 * 256) return;
  int c8 = idx % 256;                         // 16B unit within row (0..255)
  int pi = (idx / 256) % 204;
  int n  = idx / (256 * 204);
  uint4 o = make_uint4(0u, 0u, 0u, 0u);
  if (pi >= 2 && pi < 202) {
    const float* p = in + ((long long)(n * 200 + pi - 2) * 2048 + c8 * 8);
    float4 a = *(const float4*)p;
    float4 b = *(const float4*)(p + 4);
    o.x = (unsigned)f2bf_rne(a.x) | ((unsigned)f2bf_rne(a.y) << 16);
    o.y = (unsigned)f2bf_rne(a.z) | ((unsigned)f2bf_rne(a.w) << 16);
    o.z = (unsigned)f2bf_rne(b.x) | ((unsigned)f2bf_rne(b.y) << 16);
    o.w = (unsigned)f2bf_rne(b.z) | ((unsigned)f2bf_rne(b.w) << 16);
  }
  int key = (n * 204 + pi) & 7;               // absolute padded-row parity
  long long pos = ((long long)(n * 204 + pi)) * 256 + (c8 ^ key);
  *(uint4*)(out + pos * 8) = o;
}

// ---------------- zero the pad rows of a padded [n][rpad][cin] bf16 tensor ----------------
__global__ void k_zero_pad(u16* __restrict__ p, int ncnt, int rpad, int lr, int P,
                           int cin8, int total) {
  int idx = blockIdx.x * 256 + threadIdx.x;
  if (idx >= total) return;
  int c = idx % cin8;
  int pr = (idx / cin8) % (rpad - lr);
  int n = idx / (cin8 * (rpad - lr));
  int row = (pr < P) ? pr : lr + pr;
  *(uint4*)(p + ((long long)(n * rpad + row) * cin8 + c) * 8) = make_uint4(0, 0, 0, 0);
}

// ---------------- generic fp32 -> bf16 cast ----------------
__global__ void k_cast_bf16(const float* __restrict__ in, u16* __restrict__ out, int n8) {
  int idx = blockIdx.x * 256 + threadIdx.x;
  if (idx >= n8) return;
  const float4* p = (const float4*)in + (long long)idx * 2;
  float4 a = p[0], b = p[1];
  uint4 o;
  o.x = (unsigned)f2bf_rne(a.x) | ((unsigned)f2bf_rne(a.y) << 16);
  o.y = (unsigned)f2bf_rne(a.z) | ((unsigned)f2bf_rne(a.w) << 16);
  o.z = (unsigned)f2bf_rne(b.x) | ((unsigned)f2bf_rne(b.y) << 16);
  o.w = (unsigned)f2bf_rne(b.z) | ((unsigned)f2bf_rne(b.w) << 16);
  *(uint4*)(out + (long long)idx * 8) = o;
}

// conv weight [co][ci][t] -> [co][t][ci] via per-co LDS transpose.
// Coalesced float reads + packed uint4 writes (old version had 20B-stride
// scalar reads -> ~5x fetch amplification).
__global__ __launch_bounds__(256) void k_conv_w_lds(
    const float* __restrict__ in, u16* __restrict__ out, int Cin, int Kk) {
  __shared__ u16 l[10240];
  int co = blockIdx.x;
  int n = Cin * Kk;
  int tid = threadIdx.x;
  const float* src = in + (long long)co * n;
  for (int i = tid; i < n; i += 256) l[i] = f2bf_rne(src[i]);
  __syncthreads();
  u16* dst = out + (long long)co * n;
  int n8 = n >> 3;
  for (int j8 = tid; j8 < n8; j8 += 256) {
    int j = j8 * 8;
    int t = j / Cin, ci = j - t * Cin;      // 8 consecutive j share t (Cin%8==0)
    u16 tmp[8];
    #pragma unroll
    for (int e = 0; e < 8; ++e) tmp[e] = l[(ci + e) * Kk + t];
    uint4 o;
    o.x = tmp[0] | ((unsigned)tmp[1] << 16);
    o.y = tmp[2] | ((unsigned)tmp[3] << 16);
    o.z = tmp[4] | ((unsigned)tmp[5] << 16);
    o.w = tmp[6] | ((unsigned)tmp[7] << 16);
    *(uint4*)&dst[j] = o;
  }
}

// deconv weight [ci][co][4] -> per-parity conv weights [z][co][tt][ci],
// t = 3 - z - 2*tt  (z=(3-t)&1, tt=(3-t)>>1). 64x64 LDS-tiled transpose:
// coalesced float reads AND coalesced u16 writes (old version read with 8KB
// stride -> ~16x fetch amplification).
__global__ __launch_bounds__(256) void k_deconv_w_t(
    const float* __restrict__ in, u16* __restrict__ out, int Cin, int Cout) {
  __shared__ u16 l[64][65];
  int C = Cout * 4;
  int nci = Cin >> 6;
  int ci0 = (blockIdx.x % nci) << 6;
  int c0  = (blockIdx.x / nci) << 6;
  int tid = threadIdx.x;
  int cc = tid & 63, rr = tid >> 6;
  #pragma unroll 4
  for (int p = 0; p < 16; ++p) {
    int r = rr + p * 4;
    l[r][cc] = f2bf_rne(in[(long long)(ci0 + r) * C + c0 + cc]);
  }
  __syncthreads();
  #pragma unroll 4
  for (int p = 0; p < 16; ++p) {
    int cl = rr + p * 4;
    int c = c0 + cl;
    int co = c >> 2, t = c & 3;
    int z = (3 - t) & 1, tt = (3 - t) >> 1;
    out[(((long long)z * Cout + co) * 2 + tt) * Cin + ci0 + cc] = l[cc][cl];
  }
}

// ---------------- small precompute: q[z][b][c], v[z][b][c] ----------------
__global__ __launch_bounds__(256) void k_prep_small(
    const float* __restrict__ concept1, const float* __restrict__ concept2,
    const float* __restrict__ w_ca1, const float* __restrict__ w_sim1,
    const float* __restrict__ w_sim2, const float* __restrict__ w_mlp,
    float* __restrict__ qv) {
  int cz = blockIdx.x >> 2;
  int b  = blockIdx.x & 3;
  const float* con = cz ? concept2 : concept1;
  __shared__ float cvec[CDIM];
  __shared__ float chat[SDIM];
  int tid = threadIdx.x;
  for (int j = tid; j < CDIM; j += 256) cvec[j] = con[b * CDIM + j];
  __syncthreads();
  float accq = 0.f;
  for (int j = 0; j < CDIM; ++j) accq += cvec[j] * w_ca1[tid * CDIM + j];
  qv[(cz * 4 + b) * 256 + tid] = accq;
  for (int i = 0; i < 4; ++i) {
    int s = tid + i * 256;
    float a2 = 0.f;
    for (int j = 0; j < CDIM; ++j) a2 += cvec[j] * w_sim2[s * CDIM + j];
    chat[s] = a2 * w_mlp[s];
  }
  __syncthreads();
  float v = 0.f;
  for (int s = 0; s < SDIM; ++s) v += w_sim1[s * 256 + tid] * chat[s];
  qv[2048 + (cz * 4 + b) * 256 + tid] = v;
}

// ======================= conv GEMM with A-dedup (128-row tile) =======================
// R3-verified (200.9us conv1): A staged once per 64-ci block into a [160][64]
// XOR-swizzled row-major tile (spans all 5 taps: padded rows make one contiguous
// range); frag-order B; tap-inner chunks; per wave per chunk 1 A-piece + 4
// B-frags, counted vmcnt(5)/(4)/(0); double-buffered; 2 blocks/CU (72KB LDS) --
// cross-block overlap covers the DMA tail (R4 showed 1 block/CU regresses).
template <int SWZO>
__global__ __launch_bounds__(256) void k_gemm_conv(
    const u16* __restrict__ A, const u16* __restrict__ Bw,
    u16* __restrict__ Co, const float* __restrict__ bias,
    int M, int N, int Ktot, int cin, int ncib,
    int lr, int rpad, int px, int yspan, int gy,
    int orpad, int ooff, long long aend) {
  __shared__ __align__(16) u16 At[2][10240];   // [2][160][64]
  __shared__ __align__(16) u16 Bs[2][8192];
  int id = blockIdx.x;
  int k8 = id & 7, j = id >> 3;
  int x = k8 / px, h = k8 - x * px;
  int y = h * yspan + j;
  if (y >= gy) return;
  int row0 = y * 128, col0 = x * 128;
  int tid = threadIdx.x, w = tid >> 6, ln = tid & 63;
  int r15 = ln & 15, q = ln >> 4;

  int n0 = row0 / lr, l0 = row0 - n0 * lr;
  long long prow0 = (long long)n0 * rpad + l0;

  int wrb = (w >> 1) * 64;
  int rlb[4], pp[4];
  #pragma unroll
  for (int mi = 0; mi < 4; ++mi) {
    int rr = wrb + mi * 16 + r15;
    int nc = (row0 + rr) / lr - n0;
    rlb[mi] = rr + 4 * nc;
    pp[mi] = (int)((prow0 + rlb[mi]) & 7);
  }

  long long arow_base = prow0 + w * 40 + (ln >> 3);
  const u16* alim = A + (aend - 8);
  auto stA = [&](int cib_, int pc) {
    const u16* src = A + (arow_base + pc * 8) * cin + cib_ * 64 + (ln & 7) * 8;
    if (src > alim) src = alim;
    gload16(src, At[cib_ & 1] + (w * 40 + pc * 8) * 64);
  };

  const u16* gb[4];
  #pragma unroll
  for (int i = 0; i < 4; ++i) {
    int f = 4 * w + i, blk = f >> 1, ks = f & 1;
    int klocal = ks * 32 + q * 8;
    int br = col0 + blk * 16 + r15;
    gb[i] = Bw + ((long long)br * Ktot + klocal);
  }
  int wbase = 4 * w * 512;

  f32x4 acc[4][4];
  #pragma unroll
  for (int i = 0; i < 4; ++i)
    #pragma unroll
    for (int j2 = 0; j2 < 4; ++j2) acc[i][j2] = (f32x4){0.f, 0.f, 0.f, 0.f};
  int wc2 = (w & 1) * 4;

  #pragma unroll
  for (int pc = 0; pc < 5; ++pc) stA(0, pc);
  #pragma unroll
  for (int i = 0; i < 4; ++i) gload16(gb[i], Bs[0] + wbase + i * 512);
  #pragma unroll
  for (int i = 0; i < 4; ++i) gb[i] += cin;
  int ts = 1;
  asm volatile("s_waitcnt vmcnt(0)" ::: "memory");
  __builtin_amdgcn_s_barrier();

  long long bwrap = 64 - 4 * (long long)cin;
  for (int cib = 0; cib < ncib; ++cib) {
    bool lastcib = (cib == ncib - 1);
    #pragma unroll
    for (int t = 0; t < 5; ++t) {
      bool lastc = lastcib && (t == 4);
      if (!lastcib) stA(cib + 1, t);
      if (!lastc) {
        int bufn = (cib + t + 1) & 1;
        #pragma unroll
        for (int i = 0; i < 4; ++i) gload16(gb[i], Bs[bufn] + wbase + i * 512);
        long long d = (ts == 4) ? bwrap : (long long)cin;
        ts = (ts == 4) ? 0 : ts + 1;
        #pragma unroll
        for (int i = 0; i < 4; ++i) gb[i] += d;
      }
      if (lastc)        asm volatile("s_waitcnt vmcnt(0)" ::: "memory");
      else if (lastcib) asm volatile("s_waitcnt vmcnt(4)" ::: "memory");
      else              asm volatile("s_waitcnt vmcnt(5)" ::: "memory");
      __builtin_amdgcn_s_barrier();
      __builtin_amdgcn_sched_barrier(0);
      const u16* Ab = At[cib & 1];
      const u16* Bb = Bs[(cib + t) & 1];
      int rof[4], pr8[4];
      #pragma unroll
      for (int mi = 0; mi < 4; ++mi) {
        rof[mi] = (rlb[mi] + t) * 64;
        pr8[mi] = (pp[mi] + t) & 7;
      }
      #pragma unroll
      for (int ks = 0; ks < 2; ++ks) {
        bf16x8 af[4], bf[4];
        #pragma unroll
        for (int mi = 0; mi < 4; ++mi)
          af[mi] = *(const bf16x8*)&Ab[rof[mi] + (((ks * 4 + q) ^ pr8[mi]) * 8)];
        #pragma unroll
        for (int ni = 0; ni < 4; ++ni)
          bf[ni] = *(const bf16x8*)&Bb[(((wc2 + ni) * 2 + ks) * 512) + ln * 8];
        #pragma unroll
        for (int mi = 0; mi < 4; ++mi)
          #pragma unroll
          for (int ni = 0; ni < 4; ++ni)
            acc[mi][ni] = __builtin_amdgcn_mfma_f32_16x16x32_bf16(
                af[mi], bf[ni], acc[mi][ni], 0, 0, 0);
      }
      __builtin_amdgcn_sched_barrier(0);
      __builtin_amdgcn_s_barrier();
    }
  }

  int q4 = q * 4;
  int wrow = (w >> 1) * 64, wcol = (w & 1) * 64;
  int lrh = lr >> 1;
  #pragma unroll
  for (int mi = 0; mi < 4; ++mi) {
    int gbase = row0 + wrow + mi * 16 + q4;
    #pragma unroll
    for (int p = 0; p < 2; ++p) {
      int grow = gbase + 2 * p;
      if (grow < M) {
        int prow = grow >> 1;
        int n = prow / lrh, ll = prow - n * lrh;
        long long orow = (long long)n * orpad + ooff + ll;
        int key = SWZO ? ((int)(orow & 7) << 3) : 0;
        #pragma unroll
        for (int ni = 0; ni < 4; ++ni) {
          int col = col0 + wcol + ni * 16 + r15;
          float v = fmaxf(acc[mi][ni][2 * p], acc[mi][ni][2 * p + 1]) + bias[col];
          Co[orow * N + (col ^ key)] = f2bf_rne(v);
        }
      }
    }
  }
}

// ---------------- generic bf16-MFMA NT GEMM (kproj, deconvs) ----------------
#define EP_PLAIN 0
#define EP_POOL  1
#define EP_ILV   2

template <int EP>
__global__ __launch_bounds__(256) void k_gemm(
    const u16* __restrict__ A, const u16* __restrict__ Bw,
    void* __restrict__ Co, const float* __restrict__ bias,
    int M, int N, int Ktot, int nchunk,
    int lr, int rpad, int cin, int off0c, int taps,
    int px, int yspan, int gy, long long sB, int orpad, int ooff) {
  __shared__ __align__(16) u16 As[2][8192];
  __shared__ __align__(16) u16 Bs[2][8192];
  int id = blockIdx.x;
  int k8 = id & 7, j = id >> 3;
  int x = k8 / px, h = k8 - x * px;
  int y = h * yspan + j;
  if (y >= gy) return;
  int z = blockIdx.z;
  int off0 = (EP == EP_ILV) ? z : off0c;
  int row0 = y * 128, col0 = x * 128;
  int tid = threadIdx.x, w = tid >> 6, ln = tid & 63;
  const u16* Bz = Bw + (long long)z * sB;

  const u16* ga[4];
  const u16* gb[4];
  #pragma unroll
  for (int i = 0; i < 4; ++i) {
    int f = 4 * w + i, blk = f >> 1, ks = f & 1;
    int klocal = ks * 32 + (ln >> 4) * 8;
    int ar = row0 + blk * 16 + (ln & 15);
    int n_ = ar / lr, l_ = ar - n_ * lr;
    ga[i] = A + ((long long)(n_ * rpad + l_ + off0) * cin + klocal);
    int br = col0 + blk * 16 + (ln & 15);
    gb[i] = Bz + ((long long)br * Ktot + klocal);
  }
  int wbase = 4 * w * 512;

  f32x4 acc[4][4];
  #pragma unroll
  for (int i = 0; i < 4; ++i)
    #pragma unroll
    for (int j2 = 0; j2 < 4; ++j2) acc[i][j2] = (f32x4){0.f, 0.f, 0.f, 0.f};

  int wr2 = (w >> 1) * 4;
  int wc2 = (w & 1) * 4;

  long long dstep = cin;
  long long dwrap = 64 - (long long)(taps - 1) * cin;
  int tc = 0;

  #pragma unroll
  for (int i = 0; i < 4; ++i) {
    gload16(ga[i], As[0] + wbase + i * 512);
    gload16(gb[i], Bs[0] + wbase + i * 512);
  }
  {
    long long d = (tc == taps - 1) ? dwrap : dstep;
    tc = (tc == taps - 1) ? 0 : tc + 1;
    #pragma unroll
    for (int i = 0; i < 4; ++i) { ga[i] += d; gb[i] += d; }
  }

  for (int c = 0; c < nchunk; ++c) {
    int cur = c & 1;
    if (c + 1 < nchunk) {
      u16* dA = As[cur ^ 1] + wbase;
      u16* dB = Bs[cur ^ 1] + wbase;
      #pragma unroll
      for (int i = 0; i < 4; ++i) {
        gload16(ga[i], dA + i * 512);
        gload16(gb[i], dB + i * 512);
      }
      long long d = (tc == taps - 1) ? dwrap : dstep;
      tc = (tc == taps - 1) ? 0 : tc + 1;
      #pragma unroll
      for (int i = 0; i < 4; ++i) { ga[i] += d; gb[i] += d; }
      asm volatile("s_waitcnt vmcnt(8)" ::: "memory");
    } else {
      asm volatile("s_waitcnt vmcnt(0)" ::: "memory");
    }
    __builtin_amdgcn_s_barrier();
    __builtin_amdgcn_sched_barrier(0);
    #pragma unroll
    for (int ks = 0; ks < 2; ++ks) {
      bf16x8 af[4], bf[4];
      #pragma unroll
      for (int mi = 0; mi < 4; ++mi)
        af[mi] = *(const bf16x8*)&As[cur][(((wr2 + mi) * 2 + ks) * 512) + ln * 8];
      #pragma unroll
      for (int ni = 0; ni < 4; ++ni)
        bf[ni] = *(const bf16x8*)&Bs[cur][(((wc2 + ni) * 2 + ks) * 512) + ln * 8];
      #pragma unroll
      for (int mi = 0; mi < 4; ++mi)
        #pragma unroll
        for (int ni = 0; ni < 4; ++ni)
          acc[mi][ni] = __builtin_amdgcn_mfma_f32_16x16x32_bf16(
              af[mi], bf[ni], acc[mi][ni], 0, 0, 0);
    }
    __builtin_amdgcn_sched_barrier(0);
    __builtin_amdgcn_s_barrier();
  }

  int c15 = ln & 15, q4 = (ln >> 4) * 4;
  int wrow = (w >> 1) * 64, wcol = (w & 1) * 64;
  if (EP == EP_PLAIN) {
    float* Cz = (float*)Co;
    #pragma unroll
    for (int mi = 0; mi < 4; ++mi) {
      int gbase = row0 + wrow + mi * 16 + q4;
      #pragma unroll
      for (int r = 0; r < 4; ++r) {
        int grow = gbase + r;
        if (grow < M) {
          #pragma unroll
          for (int ni = 0; ni < 4; ++ni) {
            int col = col0 + wcol + ni * 16 + c15;
            Cz[(long long)grow * N + col] = acc[mi][ni][r];
          }
        }
      }
    }
  } else if (EP == EP_POOL) {
    u16* Cz = (u16*)Co;
    int lrh = lr >> 1;
    #pragma unroll
    for (int mi = 0; mi < 4; ++mi) {
      int gbase = row0 + wrow + mi * 16 + q4;
      #pragma unroll
      for (int p = 0; p < 2; ++p) {
        int grow = gbase + 2 * p;
        if (grow < M) {
          int prow = grow >> 1;
          int n = prow / lrh, ll = prow - n * lrh;
          long long orow = (long long)n * orpad + ooff + ll;
          #pragma unroll
          for (int ni = 0; ni < 4; ++ni) {
            int col = col0 + wcol + ni * 16 + c15;
            float v = fmaxf(acc[mi][ni][2 * p], acc[mi][ni][2 * p + 1]) + bias[col];
            Cz[orow * N + col] = f2bf_rne(v);
          }
        }
      }
    }
  } else {  // EP_ILV
    u16* Cz = (u16*)Co;
    #pragma unroll
    for (int mi = 0; mi < 4; ++mi) {
      int gbase = row0 + wrow + mi * 16 + q4;
      #pragma unroll
      for (int r = 0; r < 4; ++r) {
        int grow = gbase + r;
        if (grow < M) {
          int n = grow / lr, l = grow - n * lr;
          long long orow = (long long)n * orpad + ooff + 2 * l + z;
          #pragma unroll
          for (int ni = 0; ni < 4; ++ni) {
            int col = col0 + wcol + ni * 16 + c15;
            Cz[orow * N + col] = f2bf_rne(acc[mi][ni][r] + bias[col]);
          }
        }
      }
    }
  }
}

// ---------------- attention: wave-parallel scores + softmax + weighted sum ----------------
__global__ __launch_bounds__(256) void k_attention(
    const float* __restrict__ kproj, const u16* __restrict__ t2b,
    const float* __restrict__ qv, const float* __restrict__ w_ca3,
    const int* __restrict__ seg_len, u16* __restrict__ rb) {
  int bm = blockIdx.x % BM;
  int cz = blockIdx.x / BM;
  int b = bm / MM;
  int tid = threadIdx.x, w = tid >> 6, ln = tid & 63;
  __shared__ float sq[256], sw[256], sa[L4 + 14];
  sq[tid] = qv[(cz * 4 + b) * 256 + tid];
  sw[tid] = w_ca3[tid];
  __syncthreads();
  int kmax = (seg_len[bm] + 3) >> 2;
  for (int k = w; k < L4; k += 4) {
    float val = 0.f;
    #pragma unroll
    for (int i = 0; i < 4; ++i) {
      int c = ln + 64 * i;
      val += tanhf(sq[c] + kproj[(bm * L4 + k) * 256 + c]) * sw[c];
    }
    for (int off = 32; off > 0; off >>= 1) val += __shfl_down(val, off, 64);
    if (ln == 0) sa[k] = (k < kmax) ? val : -1e15f;
  }
  __syncthreads();
  if (w == 0) {
    float sv = (ln < L4) ? sa[ln] : -3e38f;
    float mx = sv;
    for (int off = 32; off > 0; off >>= 1) mx = fmaxf(mx, __shfl_down(mx, off, 64));
    mx = __shfl(mx, 0, 64);
    float e = (ln < L4) ? expf(sv - mx) : 0.f;
    float s = e;
    for (int off = 32; off > 0; off >>= 1) s += __shfl_down(s, off, 64);
    s = __shfl(s, 0, 64);
    if (ln < L4) sa[ln] = e / s;
  }
  __syncthreads();
  float r = 0.f;
  for (int k = 0; k < L4; ++k) r += sa[k] * bf2f(t2b[(bm * L4 + k) * 256 + tid]);
  rb[(cz * BM + bm) * 256 + tid] = f2bf_rne(r);
}

// ---------------- build cat matrix, padded [80][52][768] bf16, interior rows 1..50 ----------------
__global__ void k_build_cat(const u16* __restrict__ t2b, const u16* __restrict__ rb,
                            u16* __restrict__ catm, int total) {
  int idx = blockIdx.x * 256 + threadIdx.x;
  if (idx >= total) return;
  int ci = idx % 768;
  int row = idx / 768;        // bm*50 + li
  int bm = row / L4, li = row - bm * L4;
  u16 v;
  if (ci < 256)      v = t2b[row * 256 + ci];
  else if (ci < 512) v = rb[bm * 256 + (ci - 256)];
  else               v = rb[(BM + bm) * 256 + (ci - 512)];
  catm[((long long)(bm * 52 + 1 + li)) * 768 + ci] = v;
}

// ---------------- final projection + sigmoid: wave-per-row GEMV ----------------
// 250 blocks x 4 waves x 16 rows (4000%16==0 -> a 16-row window never spans
// two b's). Lane ln holds 4 row elements + 4 q-elements of each concept;
// coalesced ushort4 row loads, 12 shfls/row. Replaces block-per-row version
// (16000 tiny blocks, latency-bound).
__global__ __launch_bounds__(256) void k_final(
    const u16* __restrict__ d2b, const float* __restrict__ qv,
    const float* __restrict__ b_mlp, float* __restrict__ out) {
  int wv = blockIdx.x * 4 + (threadIdx.x >> 6);
  int ln = threadIdx.x & 63;
  int row0 = wv * 16;
  int b = row0 / 4000;
  float4 q1 = *(const float4*)&qv[2048 + b * 256 + ln * 4];
  float4 q2 = *(const float4*)&qv[2048 + 1024 + b * 256 + ln * 4];
  float bmlp = b_mlp[0];
  for (int r = 0; r < 16; ++r) {
    int row = row0 + r;
    ushort4 v = *(const ushort4*)&d2b[(long long)row * 256 + ln * 4];
    float x0 = bf2f(v.x), x1 = bf2f(v.y), x2 = bf2f(v.z), x3 = bf2f(v.w);
    float p1 = x0 * q1.x + x1 * q1.y + x2 * q1.z + x3 * q1.w;
    float p2 = x0 * q2.x + x1 * q2.y + x2 * q2.z + x3 * q2.w;
    for (int off = 32; off > 0; off >>= 1) {
      p1 += __shfl_down(p1, off, 64);
      p2 += __shfl_down(p2, off, 64);
    }
    if (ln == 0) {
      out[row]         = 1.f / (1.f + expf(-(p1 + bmlp)));
      out[16000 + row] = 1.f / (1.f + expf(-(p2 + bmlp)));
    }
  }
}

// ---------------- host ----------------
extern "C" void kernel_launch(void* const* d_in, const int* in_sizes, int n_in,
                              void* d_out, int out_size, void* d_ws, size_t ws_size,
                              hipStream_t stream) {
  const float* batch    = (const float*)d_in[0];
  const int*   seg_len  = (const int*)d_in[1];
  const float* concept1 = (const float*)d_in[2];
  const float* concept2 = (const float*)d_in[3];
  const float* w_conv1  = (const float*)d_in[4];
  const float* b_conv1  = (const float*)d_in[5];
  const float* w_conv2  = (const float*)d_in[6];
  const float* b_conv2  = (const float*)d_in[7];
  const float* w_ca1    = (const float*)d_in[8];
  const float* w_ca2    = (const float*)d_in[9];
  const float* w_ca3    = (const float*)d_in[10];
  const float* w_dc1    = (const float*)d_in[11];
  const float* b_dc1    = (const float*)d_in[12];
  const float* w_dc2    = (const float*)d_in[13];
  const float* b_dc2    = (const float*)d_in[14];
  const float* w_sim1   = (const float*)d_in[15];
  const float* w_sim2   = (const float*)d_in[16];
  const float* w_mlp    = (const float*)d_in[17];
  const float* b_mlp    = (const float*)d_in[18];
  float* out = (float*)d_out;

  float* ws = (float*)d_ws;
  // workspace (float units) — total 24,477,696 f = 97.9 MB
  const long long off_qv    = 0;          //      4,096
  const long long off_kproj = 4096;       //  1,024,000 fp32
  const long long off_rb    = 1028096;    //     20,480 (u16 40,960)
  const long long off_t1    = 1048576;    //  2,162,688 (t1b [80][104][512]+slack)
  const long long off_t2    = 3211264;    //    524,288 (t2b [4000][256]+slack)
  const long long off_w1b   = 3735552;    //  2,621,440
  const long long off_w2b   = 6356992;    //    327,680
  const long long off_wd1p  = 6684672;    //    786,432
  const long long off_wd2p  = 7471104;    //    262,144
  const long long off_wca2b = 7733248;    //     32,768
  const long long off_BIG   = 7766016;    // 16,711,680 (batchb -> catm/d1b/d2b)

  u16* rb    = (u16*)(ws + off_rb);
  u16* t1b   = (u16*)(ws + off_t1);
  u16* t2b   = (u16*)(ws + off_t2);
  u16* w1b   = (u16*)(ws + off_w1b);
  u16* w2b   = (u16*)(ws + off_w2b);
  u16* wd1p  = (u16*)(ws + off_wd1p);
  u16* wd2p  = (u16*)(ws + off_wd2p);
  u16* wca2b = (u16*)(ws + off_wca2b);
  u16* batchb = (u16*)(ws + off_BIG);               // [80][204][2048] swizzled
  u16* catm   = (u16*)(ws + off_BIG);               // [80][52][768]+slack (after conv1)
  u16* d1b    = (u16*)(ws + off_BIG) + 3342336;     // [80][102][512]+slack
  u16* d2b    = (u16*)(ws + off_BIG) + 7667712;     // [16000][256]

  // --- prep: padded+swizzled bf16 batch, bf16 weights, small vectors ---
  k_cast_pad_batch<<<dim3(16320), 256, 0, stream>>>(batch, batchb);
  k_conv_w_lds<<<dim3(512), 256, 0, stream>>>(w_conv1, w1b, INC, 5);
  k_conv_w_lds<<<dim3(256), 256, 0, stream>>>(w_conv2, w2b, C1, 5);
  k_deconv_w_t<<<dim3(384), 256, 0, stream>>>(w_dc1, wd1p, 3 * C2, DC1);
  k_deconv_w_t<<<dim3(128), 256, 0, stream>>>(w_dc2, wd2p, DC1, DC2);
  k_cast_bf16<<<dim3(32), 256, 0, stream>>>(w_ca2, wca2b, 8192);
  k_prep_small<<<dim3(8), 256, 0, stream>>>(concept1, concept2, w_ca1, w_sim1, w_sim2,
                                            w_mlp, ws + off_qv);
  k_zero_pad<<<dim3(80), 256, 0, stream>>>(t1b, 80, 104, 100, 2, 64, 20480);

  // --- conv1 + pool + bias -> t1b [80][104][512] SWIZZLED (M=16000,N=512,K=10240)
  // A-dedup conv GEMM; gx=4 -> px=2, yspan=63, grid 504; ncib = 2048/64 = 32
  k_gemm_conv<1><<<dim3(504), 256, 0, stream>>>(
      batchb, w1b, t1b, b_conv1, 16000, 512, 10240, 2048, 32,
      200, 204, 2, 63, 125, 104, 2, 80LL * 204 * 2048);

  // batchb dead -> zero pads of catm / d1b (they overlay it)
  k_zero_pad<<<dim3(60), 256, 0, stream>>>(catm, 80, 52, 50, 1, 96, 15360);
  k_zero_pad<<<dim3(40), 256, 0, stream>>>(d1b, 80, 102, 100, 1, 64, 10240);

  // --- conv2 + pool + bias -> t2b [4000][256] plain (M=8000,N=256,K=2560)
  // ncib = 512/64 = 8; gx=2 -> px=4, yspan=16, grid 128
  k_gemm_conv<0><<<dim3(128), 256, 0, stream>>>(
      t1b, w2b, t2b, b_conv2, 8000, 256, 2560, 512, 8,
      100, 104, 4, 16, 63, 50, 0, 80LL * 104 * 512);

  // --- kproj = t2 @ w_ca2^T -> fp32 [4000][256] (M=4000,N=256,K=256)
  k_gemm<EP_PLAIN><<<dim3(64), 256, 0, stream>>>(
      t2b, wca2b, ws + off_kproj, nullptr, 4000, 256, 256, 4,
      4000, 4000, 256, 0, 1, 4, 8, 32, 0, 0, 0);

  // --- attention -> rb bf16 [2][80][256]
  k_attention<<<dim3(160), 256, 0, stream>>>(ws + off_kproj, t2b, ws + off_qv,
                                             w_ca3, seg_len, rb);

  // --- cat -> catm padded [80][52][768]
  k_build_cat<<<dim3(12000), 256, 0, stream>>>(t2b, rb, catm, 4000 * 768);

  // --- deconv1: 2 parity convs + bias -> d1b [80][102][512] (M=4000,N=512,K=1536)
  k_gemm<EP_ILV><<<dim3(128, 1, 2), 256, 0, stream>>>(
      catm, wd1p, d1b, b_dc1, 4000, 512, 1536, 24,
      50, 52, 768, 0, 2, 2, 16, 32, 786432LL, 102, 1);

  // --- deconv2: 2 parity convs + bias -> d2b [16000][256] (M=8000,N=256,K=1024)
  k_gemm<EP_ILV><<<dim3(128, 1, 2), 256, 0, stream>>>(
      d1b, wd2p, d2b, b_dc2, 8000, 256, 1024, 16,
      100, 102, 512, 0, 2, 4, 16, 63, 262144LL, 200, 0);

  // --- final dot + sigmoid -> out (sc1 | sc2) fp32
  k_final<<<dim3(250), 256, 0, stream>>>(d2b, ws + off_qv, b_mlp, out);
}